// Round 5
// baseline (363.555 us; speedup 1.0000x reference)
//
#include <hip/hip_runtime.h>

// ImageWiseConv2d: per-sample conv, images [64,64,128,128] f32, kernels [64,64,3,3] f32
// out [64,1,126,126] f32 (VALID, stride 1).
//
// R5 = R4's spill-free direct-global register kernel + split-K over channels for TLP.
// Evidence: R0 (LDS, 2 blk/CU) and R4 (no-LDS, 2 blk/CU) both ~105 us at ~3 TB/s; the
// fill kernel hits 6.5 TB/s -> we are concurrency(latency)-bound, not pattern-bound.
// NG=4 groups -> 2048 blocks -> ~5-8 blocks/CU (20-28 waves/CU) vs R4's 8 waves/CU.
// launch_bounds(256,2): generous VGPR budget; R1/R2 regressions were launch-bounds-forced
// scratch spills (WRITE_SIZE 663/841 MB) -- do NOT tighten this.
// Partials [4][64][126][128] f32 in d_ws (padded stride -> aligned unguarded float4),
// reduce kernel sums 4 groups (+37 MB traffic, +12% over the 307 MB floor).

#define NS   64
#define CCH  64
#define HH   128
#define WW   128
#define OHH  126
#define OWW  126
#define CHS  (HH * WW)   // floats per channel plane
#define NG   4           // channel groups
#define CPG  16          // channels per group
#define PSTR 128         // padded partial row stride (floats)

__global__ __launch_bounds__(256, 2)
void ImageWiseConv2d_main(const float* __restrict__ img,
                          const float* __restrict__ ker,
                          float* __restrict__ part)
{
    const int tid = threadIdx.x;
    const int bx  = blockIdx.x;          // 0..2047
    const int bt  = bx & 7;              // row tile (16 output rows)
    const int n   = (bx >> 3) & 63;      // sample
    const int g   = bx >> 9;             // channel group 0..3
    const int h0  = bt * 16;

    const int r0 = (tid >> 5) << 1;      // patch top output row within tile: 0..14
    const int c0 = (tid & 31) << 2;      // patch left output col: 0..124

    // input rows ihr..ihr+3; clamp (clamped case bt=7,r0=14 feeds discarded outputs)
    int ihr = h0 + r0;
    if (ihr > HH - 4) ihr = HH - 4;
    // float2 tail at cols c0+4,c0+5; c0=124 clamps to 126,127 (feeds discarded cols)
    const int bOff = (c0 < 124) ? 4 : 2;

    const int cb = n * CCH + g * CPG;    // base channel
    const float* p0 = img + ((cb * HH) + ihr) * WW + c0;
    const float* kp = ker + cb * 9;      // block-uniform -> scalar loads

    float a00 = 0.f, a01 = 0.f, a02 = 0.f, a03 = 0.f;
    float a10 = 0.f, a11 = 0.f, a12 = 0.f, a13 = 0.f;

    float4 A0, A1, A2, A3;
    float2 B0, B1, B2, B3;
    A0 = *(const float4*)(p0);
    A1 = *(const float4*)(p0 + WW);
    A2 = *(const float4*)(p0 + 2 * WW);
    A3 = *(const float4*)(p0 + 3 * WW);
    B0 = *(const float2*)(p0 + bOff);
    B1 = *(const float2*)(p0 + WW + bOff);
    B2 = *(const float2*)(p0 + 2 * WW + bOff);
    B3 = *(const float2*)(p0 + 3 * WW + bOff);

    for (int c = 0; c < CPG; ++c) {
        float4 nA0, nA1, nA2, nA3;
        float2 nB0, nB1, nB2, nB3;
        const bool more = (c + 1 < CPG);
        if (more) {
            const float* q = p0 + (c + 1) * CHS;
            nA0 = *(const float4*)(q);
            nA1 = *(const float4*)(q + WW);
            nA2 = *(const float4*)(q + 2 * WW);
            nA3 = *(const float4*)(q + 3 * WW);
            nB0 = *(const float2*)(q + bOff);
            nB1 = *(const float2*)(q + WW + bOff);
            nB2 = *(const float2*)(q + 2 * WW + bOff);
            nB3 = *(const float2*)(q + 3 * WW + bOff);
        }

        const float w0 = kp[c * 9 + 0], w1 = kp[c * 9 + 1], w2 = kp[c * 9 + 2];
        const float w3 = kp[c * 9 + 3], w4 = kp[c * 9 + 4], w5 = kp[c * 9 + 5];
        const float w6 = kp[c * 9 + 6], w7 = kp[c * 9 + 7], w8 = kp[c * 9 + 8];

        {   // row 0 -> acc0 (kr0)
            const float v0 = A0.x, v1 = A0.y, v2 = A0.z, v3 = A0.w, v4 = B0.x, v5 = B0.y;
            a00 = fmaf(w0, v0, a00); a00 = fmaf(w1, v1, a00); a00 = fmaf(w2, v2, a00);
            a01 = fmaf(w0, v1, a01); a01 = fmaf(w1, v2, a01); a01 = fmaf(w2, v3, a01);
            a02 = fmaf(w0, v2, a02); a02 = fmaf(w1, v3, a02); a02 = fmaf(w2, v4, a02);
            a03 = fmaf(w0, v3, a03); a03 = fmaf(w1, v4, a03); a03 = fmaf(w2, v5, a03);
        }
        {   // row 1 -> acc0 (kr1), acc1 (kr0)
            const float v0 = A1.x, v1 = A1.y, v2 = A1.z, v3 = A1.w, v4 = B1.x, v5 = B1.y;
            a00 = fmaf(w3, v0, a00); a00 = fmaf(w4, v1, a00); a00 = fmaf(w5, v2, a00);
            a01 = fmaf(w3, v1, a01); a01 = fmaf(w4, v2, a01); a01 = fmaf(w5, v3, a01);
            a02 = fmaf(w3, v2, a02); a02 = fmaf(w4, v3, a02); a02 = fmaf(w5, v4, a02);
            a03 = fmaf(w3, v3, a03); a03 = fmaf(w4, v4, a03); a03 = fmaf(w5, v5, a03);
            a10 = fmaf(w0, v0, a10); a10 = fmaf(w1, v1, a10); a10 = fmaf(w2, v2, a10);
            a11 = fmaf(w0, v1, a11); a11 = fmaf(w1, v2, a11); a11 = fmaf(w2, v3, a11);
            a12 = fmaf(w0, v2, a12); a12 = fmaf(w1, v3, a12); a12 = fmaf(w2, v4, a12);
            a13 = fmaf(w0, v3, a13); a13 = fmaf(w1, v4, a13); a13 = fmaf(w2, v5, a13);
        }
        {   // row 2 -> acc0 (kr2), acc1 (kr1)
            const float v0 = A2.x, v1 = A2.y, v2 = A2.z, v3 = A2.w, v4 = B2.x, v5 = B2.y;
            a00 = fmaf(w6, v0, a00); a00 = fmaf(w7, v1, a00); a00 = fmaf(w8, v2, a00);
            a01 = fmaf(w6, v1, a01); a01 = fmaf(w7, v2, a01); a01 = fmaf(w8, v3, a01);
            a02 = fmaf(w6, v2, a02); a02 = fmaf(w7, v3, a02); a02 = fmaf(w8, v4, a02);
            a03 = fmaf(w6, v3, a03); a03 = fmaf(w7, v4, a03); a03 = fmaf(w8, v5, a03);
            a10 = fmaf(w3, v0, a10); a10 = fmaf(w4, v1, a10); a10 = fmaf(w5, v2, a10);
            a11 = fmaf(w3, v1, a11); a11 = fmaf(w4, v2, a11); a11 = fmaf(w5, v3, a11);
            a12 = fmaf(w3, v2, a12); a12 = fmaf(w4, v3, a12); a12 = fmaf(w5, v4, a12);
            a13 = fmaf(w3, v3, a13); a13 = fmaf(w4, v4, a13); a13 = fmaf(w5, v5, a13);
        }
        {   // row 3 -> acc1 (kr2)
            const float v0 = A3.x, v1 = A3.y, v2 = A3.z, v3 = A3.w, v4 = B3.x, v5 = B3.y;
            a10 = fmaf(w6, v0, a10); a10 = fmaf(w7, v1, a10); a10 = fmaf(w8, v2, a10);
            a11 = fmaf(w6, v1, a11); a11 = fmaf(w7, v2, a11); a11 = fmaf(w8, v3, a11);
            a12 = fmaf(w6, v2, a12); a12 = fmaf(w7, v3, a12); a12 = fmaf(w8, v4, a12);
            a13 = fmaf(w6, v3, a13); a13 = fmaf(w7, v4, a13); a13 = fmaf(w8, v5, a13);
        }

        if (more) {
            A0 = nA0; A1 = nA1; A2 = nA2; A3 = nA3;
            B0 = nB0; B1 = nB1; B2 = nB2; B3 = nB3;
        }
    }

    // ---- store 2x4 partials (PSTR=128 -> 16B-aligned float4, no col guard) ----
    const int oh0 = h0 + r0;
    if (oh0 < OHH) {
        float* pp = part + (((g * NS + n) * OHH) + oh0) * PSTR + c0;
        *(float4*)pp = make_float4(a00, a01, a02, a03);
    }
    if (oh0 + 1 < OHH) {
        float* pp = part + (((g * NS + n) * OHH) + oh0 + 1) * PSTR + c0;
        *(float4*)pp = make_float4(a10, a11, a12, a13);
    }
}

__global__ __launch_bounds__(256)
void ImageWiseConv2d_reduce(const float* __restrict__ part,
                            float* __restrict__ out)
{
    const int i = blockIdx.x * 256 + threadIdx.x;
    const int total = NS * OHH * OWW;          // 1,016,064
    if (i >= total) return;
    const int n  = i / (OHH * OWW);
    const int r  = i - n * (OHH * OWW);
    const int oh = r / OWW;
    const int ow = r - oh * OWW;
    const int gs = NS * OHH * PSTR;            // per-group stride
    const int pb = (n * OHH + oh) * PSTR + ow;
    out[i] = (part[pb] + part[pb + gs]) + (part[pb + 2 * gs] + part[pb + 3 * gs]);
}

extern "C" void kernel_launch(void* const* d_in, const int* in_sizes, int n_in,
                              void* d_out, int out_size, void* d_ws, size_t ws_size,
                              hipStream_t stream) {
    const float* img = (const float*)d_in[0];   // [64,64,128,128] f32
    const float* ker = (const float*)d_in[1];   // [64,64,3,3] f32
    float* out  = (float*)d_out;                // [64,1,126,126] f32
    float* part = (float*)d_ws;                 // [4][64][126][128] f32 = 16.5 MB

    ImageWiseConv2d_main<<<dim3(NG * NS * 8), dim3(256), 0, stream>>>(img, ker, part);

    const int total = NS * OHH * OWW;
    ImageWiseConv2d_reduce<<<dim3((total + 255) / 256), dim3(256), 0, stream>>>(part, out);
}